// Round 1
// 334.961 us; speedup vs baseline: 1.0467x; 1.0467x over previous
//
#include <hip/hip_runtime.h>
#include <stdint.h>

#define DI __device__ __forceinline__

using floatx4 = __attribute__((ext_vector_type(4))) float;
using short8  = __attribute__((ext_vector_type(8))) short;   // 8 bf16 in 4 VGPRs

DI uint16_t f2b(float f) {  // fp32 -> bf16 round-to-nearest-even
  uint32_t u = __float_as_uint(f);
  return (uint16_t)((u + 0x7FFFu + ((u >> 16) & 1u)) >> 16);
}

DI void async_cp16(const uint16_t* g, uint16_t* l) {
  // 16B per lane, LDS dest = wave-uniform base + lane*16 (no padding allowed)
  __builtin_amdgcn_global_load_lds(
      (const __attribute__((address_space(1))) void*)g,
      (__attribute__((address_space(3))) void*)l, 16, 0, 0);
}

// ---------------------------------------------------------------- X fp32->bf16
__global__ __launch_bounds__(256)
void cvt_bf16(const float* __restrict__ x, uint16_t* __restrict__ y) {
  long i = ((long)blockIdx.x * 256 + threadIdx.x) * 8;
  float4 a = *(const float4*)(x + i);
  float4 b = *(const float4*)(x + i + 4);
  union { uint16_t u[8]; uint4 v; } o;
  o.u[0] = f2b(a.x); o.u[1] = f2b(a.y); o.u[2] = f2b(a.z); o.u[3] = f2b(a.w);
  o.u[4] = f2b(b.x); o.u[5] = f2b(b.y); o.u[6] = f2b(b.z); o.u[7] = f2b(b.w);
  *(uint4*)(y + i) = o.v;
}

// ------------------------------------------------- T1[(ijkl)][b] = g0 x g1
// T1 as (ij)x(klb): T1[ij*16384 + klb] = sum_a g0[ij*64+a]*g1[a*16384+klb]
// Same memory as [(ijk)][(lb)] row-major 4096x1024.
__global__ __launch_bounds__(256)
void tt_t1(const float* __restrict__ g0, const float* __restrict__ g1,
           uint16_t* __restrict__ t1) {
  __shared__ float g0s[64 * 64];    // [row][a]  16KB
  __shared__ float g1s[64 * 128];   // [a][col]  32KB
  const int rowbase = blockIdx.x * 64;
  const int colbase = blockIdx.y * 128;
  const int t = threadIdx.x;

  for (int f = t; f < 4096; f += 256) g0s[f] = g0[rowbase * 64 + f];
  for (int f = t; f < 8192; f += 256) {
    int a = f >> 7, c = f & 127;
    g1s[f] = g1[(long)a * 16384 + colbase + c];
  }
  __syncthreads();

  const int tx = t & 31;
  const int ty = t >> 5;
  const int c0 = tx * 4;
  const int r0 = ty * 8;

  float acc[8][4];
  #pragma unroll
  for (int r = 0; r < 8; ++r)
    #pragma unroll
    for (int c = 0; c < 4; ++c) acc[r][c] = 0.f;

  for (int a4 = 0; a4 < 16; ++a4) {
    float g0r[8][4];
    #pragma unroll
    for (int r = 0; r < 8; ++r)
      *(float4*)&g0r[r][0] = *(const float4*)&g0s[(r0 + r) * 64 + a4 * 4];
    #pragma unroll
    for (int e = 0; e < 4; ++e) {
      float4 bv4 = *(const float4*)&g1s[(a4 * 4 + e) * 128 + c0];
      float bv[4] = {bv4.x, bv4.y, bv4.z, bv4.w};
      #pragma unroll
      for (int r = 0; r < 8; ++r)
        #pragma unroll
        for (int c = 0; c < 4; ++c)
          acc[r][c] += g0r[r][e] * bv[c];
    }
  }

  #pragma unroll
  for (int r = 0; r < 8; ++r) {
    ushort4 o;
    o.x = f2b(acc[r][0]); o.y = f2b(acc[r][1]);
    o.z = f2b(acc[r][2]); o.w = f2b(acc[r][3]);
    *(ushort4*)&t1[(long)(rowbase + r0 + r) * 16384 + colbase + c0] = o;
  }
}

// ------------------------------------------------- T1 (4096x1024) -> T1t (1024x4096)
// LDS-tiled transpose; blocks with y==0 also build g2t[(mn)][b] = g2[b][(mn)].
__global__ __launch_bounds__(256)
void transpose_t1(const uint16_t* __restrict__ src, uint16_t* __restrict__ dst,
                  const float* __restrict__ g2, uint16_t* __restrict__ g2t) {
  __shared__ uint16_t tile[64][68];
  const int cb = blockIdx.x * 64;     // col tile in src (lb dim, 1024)
  const int rb = blockIdx.y * 64;     // row tile in src (ijk dim, 4096)
  const int t = threadIdx.x;

  if (blockIdx.y == 0) {              // side job: 16 blocks x 1024 elems
    #pragma unroll
    for (int p = 0; p < 4; ++p) {
      int f = blockIdx.x * 1024 + p * 256 + t;   // 0..16383
      int mn = f >> 6, b = f & 63;
      g2t[f] = f2b(g2[b * 256 + mn]);
    }
  }
  {
    const int c4 = (t & 15) * 4;
    const int r  = t >> 4;
    #pragma unroll
    for (int p = 0; p < 4; ++p) {
      int rr = r + p * 16;
      *(ushort4*)&tile[rr][c4] = *(const ushort4*)&src[(long)(rb + rr) * 1024 + cb + c4];
    }
  }
  __syncthreads();
  {
    const int r4 = (t & 15) * 4;
    const int c  = t >> 4;
    #pragma unroll
    for (int p = 0; p < 4; ++p) {
      int cc = c + p * 16;
      ushort4 o;
      o.x = tile[r4 + 0][cc]; o.y = tile[r4 + 1][cc];
      o.z = tile[r4 + 2][cc]; o.w = tile[r4 + 3][cc];
      *(ushort4*)&dst[(long)(cb + cc) * 4096 + rb + r4] = o;
    }
  }
}

// ------------------------------------------------- fused V=Xbf@T1 then out=V@g2+bias
// Phase 1: 128x128 tile over K=4096, BK=64 stored as TWO [128][32] half-tiles
//   (64B row pitch -> identical bank profile to the proven BK=32 layout; no swizzle).
//   DOUBLE-BUFFERED: tile t+1's global_load_lds issued before compute of tile t,
//   single __syncthreads per 64-K step (its vmcnt(0) drain lands ~1.5k cyc after
//   issue -> load latency fully hidden under ds_read+MFMA). 65 barriers vs 256.
// Phase 2: V-tile -> LDS Vs (bf16, VSTRIDE=136 padded) -> MFMA vs g2t -> out + bias.
// LDS union: Vs (34.8KB) aliases the 64KB staging double-buffer (phase 1 is done).
#define VSTRIDE 136

DI void compute_half(const uint16_t* __restrict__ as_, const uint16_t* __restrict__ bs_,
                     int wm, int wn, int fr, int fk, floatx4 acc[4][4]) {
  short8 af[4], bg[4];
  #pragma unroll
  for (int i = 0; i < 4; ++i)
    af[i] = *(const short8*)&as_[(wm + i * 16 + fr) * 32 + fk];
  #pragma unroll
  for (int j = 0; j < 4; ++j)
    bg[j] = *(const short8*)&bs_[(wn + j * 16 + fr) * 32 + fk];
  #pragma unroll
  for (int i = 0; i < 4; ++i)
    #pragma unroll
    for (int j = 0; j < 4; ++j)
      acc[i][j] = __builtin_amdgcn_mfma_f32_16x16x32_bf16(af[i], bg[j], acc[i][j], 0, 0, 0);
}

DI void stage_tile(const uint16_t* __restrict__ Ab, const uint16_t* __restrict__ Bb,
                   uint16_t* dstbuf, int k0, int wave, int srow, int scol) {
  // dstbuf layout (shorts): A[2][128][32] at [0,8192), B[2][128][32] at [8192,16384)
  #pragma unroll
  for (int ks = 0; ks < 2; ++ks)
    #pragma unroll
    for (int t = 0; t < 2; ++t) {
      const int rblk = wave * 2 + t;      // 16-row chunk, 1KB per cp16 issue
      async_cp16(Ab + (long)(rblk * 16 + srow) * 4096 + k0 + ks * 32 + scol,
                 dstbuf + ks * 4096 + rblk * 16 * 32);
      async_cp16(Bb + (long)(rblk * 16 + srow) * 4096 + k0 + ks * 32 + scol,
                 dstbuf + 8192 + ks * 4096 + rblk * 16 * 32);
    }
}

__global__ __launch_bounds__(256, 2)
void gemm_fused(const uint16_t* __restrict__ A,    // Xbf 8192x4096
                const uint16_t* __restrict__ Bt,   // T1t 1024x4096 (k-contig)
                const uint16_t* __restrict__ g2t,  // 256x64 (k=b contig)
                const float* __restrict__ bias,
                float* __restrict__ out) {
  // 64KB LDS union: phase-1 dbuf (2 x 16384 shorts) / phase-2 Vs[128][VSTRIDE]
  __shared__ __align__(16) uint16_t lds[32768];
  uint16_t* buf0 = lds;
  uint16_t* buf1 = lds + 16384;

  const int bm = blockIdx.x * 128;
  const int bn = blockIdx.y * 128;      // V-col base: l0 = bn/64 = 2*blockIdx.y
  const int tid  = threadIdx.x;
  const int wave = tid >> 6;
  const int lane = tid & 63;
  const int wm = (wave >> 1) * 64;
  const int wn = (wave & 1) * 64;

  const uint16_t* Ab = A + (long)bm * 4096;
  const uint16_t* Bb = Bt + (long)bn * 4096;

  const int srow = lane >> 2;           // staging: 16 rows x 64B per wave-issue
  const int scol = (lane & 3) * 8;
  const int fr = lane & 15;             // fragment row (m or n)
  const int fk = (lane >> 4) * 8;       // fragment k offset

  floatx4 acc[4][4];
  #pragma unroll
  for (int i = 0; i < 4; ++i)
    #pragma unroll
    for (int j = 0; j < 4; ++j)
      acc[i][j] = (floatx4){0.f, 0.f, 0.f, 0.f};

  // ---- pipelined K-loop: 64 tiles of BK=64, prefetch depth 1
  stage_tile(Ab, Bb, buf0, 0, wave, srow, scol);
  __syncthreads();                       // drains prologue loads (vmcnt(0)+barrier)

  for (int t = 0; t < 62; t += 2) {
    stage_tile(Ab, Bb, buf1, (t + 1) * 64, wave, srow, scol);   // issue next
    compute_half(buf0,        buf0 + 8192,  wm, wn, fr, fk, acc);
    compute_half(buf0 + 4096, buf0 + 12288, wm, wn, fr, fk, acc);
    __syncthreads();                     // drains buf1 loads; buf0 reads done

    stage_tile(Ab, Bb, buf0, (t + 2) * 64, wave, srow, scol);
    compute_half(buf1,        buf1 + 8192,  wm, wn, fr, fk, acc);
    compute_half(buf1 + 4096, buf1 + 12288, wm, wn, fr, fk, acc);
    __syncthreads();
  }
  stage_tile(Ab, Bb, buf1, 63 * 64, wave, srow, scol);          // last tile
  compute_half(buf0,        buf0 + 8192,  wm, wn, fr, fk, acc); // tile 62
  compute_half(buf0 + 4096, buf0 + 12288, wm, wn, fr, fk, acc);
  __syncthreads();
  compute_half(buf1,        buf1 + 8192,  wm, wn, fr, fk, acc); // tile 63
  compute_half(buf1 + 4096, buf1 + 12288, wm, wn, fr, fk, acc);

  // ---- phase-1 epilogue: acc (C-layout) -> Vs bf16 row-major [128][VSTRIDE]
  const int colq = lane & 15;
  const int rowq = (lane >> 4) * 4;
  __syncthreads();                       // all waves' last ds_reads done (union safety)
  #pragma unroll
  for (int i = 0; i < 4; ++i)
    #pragma unroll
    for (int j = 0; j < 4; ++j)
      #pragma unroll
      for (int r = 0; r < 4; ++r)
        lds[(wm + i * 16 + rowq + r) * VSTRIDE + wn + j * 16 + colq] = f2b(acc[i][j][r]);
  __syncthreads();

  // ---- phase 2: out[row][l*256+mn] = sum_b Vs[row][(l-l0)*64+b] * g2t[mn][b] + bias
  // wave w: l = l0 + (w>>1), mn in [(w&1)*128, +128)
  const int bsel   = (wave >> 1) * 64;      // Vs col base (b-dim)
  const int mnBase = (wave & 1) * 128;      // g2t row base
  const long ocol0 = (long)blockIdx.y * 512 + (wave >> 1) * 256 + mnBase;

  short8 bg2[8][2];
  #pragma unroll
  for (int jn = 0; jn < 8; ++jn)
    #pragma unroll
    for (int ks = 0; ks < 2; ++ks)
      bg2[jn][ks] = *(const short8*)&g2t[(mnBase + jn * 16 + fr) * 64 + ks * 32 + fk];

  float bvs[8];
  #pragma unroll
  for (int jn = 0; jn < 8; ++jn)
    bvs[jn] = bias[ocol0 + jn * 16 + colq];

  #pragma unroll
  for (int pass = 0; pass < 4; ++pass) {
    floatx4 acc2[2][8];
    #pragma unroll
    for (int im = 0; im < 2; ++im)
      #pragma unroll
      for (int jn = 0; jn < 8; ++jn)
        acc2[im][jn] = (floatx4){0.f, 0.f, 0.f, 0.f};

    short8 af2[2][2];
    #pragma unroll
    for (int im = 0; im < 2; ++im)
      #pragma unroll
      for (int ks = 0; ks < 2; ++ks)
        af2[im][ks] = *(const short8*)&lds[(pass * 32 + im * 16 + fr) * VSTRIDE + bsel + ks * 32 + fk];

    #pragma unroll
    for (int im = 0; im < 2; ++im)
      #pragma unroll
      for (int jn = 0; jn < 8; ++jn)
        #pragma unroll
        for (int ks = 0; ks < 2; ++ks)
          acc2[im][jn] = __builtin_amdgcn_mfma_f32_16x16x32_bf16(af2[im][ks], bg2[jn][ks], acc2[im][jn], 0, 0, 0);

    #pragma unroll
    for (int jn = 0; jn < 8; ++jn)
      #pragma unroll
      for (int im = 0; im < 2; ++im)
        #pragma unroll
        for (int r = 0; r < 4; ++r) {
          const int row = bm + pass * 32 + im * 16 + rowq + r;
          out[(long)row * 4096 + ocol0 + jn * 16 + colq] = acc2[im][jn][r] + bvs[jn];
        }
  }
}

// ---------------------------------------------------------------- launch
// ws layout (bytes): Xbf 64MB | T1 8MB | T1t 8MB | g2t 32KB  (~80MB)
static constexpr long XBF_OFF = 0;
static constexpr long T1_OFF  = 67108864;
static constexpr long T1T_OFF = 75497472;
static constexpr long G2T_OFF = 83886080;

extern "C" void kernel_launch(void* const* d_in, const int* in_sizes, int n_in,
                              void* d_out, int out_size, void* d_ws, size_t ws_size,
                              hipStream_t stream) {
  const float* x    = (const float*)d_in[0];
  const float* g0   = (const float*)d_in[1];
  const float* g1   = (const float*)d_in[2];
  const float* g2   = (const float*)d_in[3];
  const float* bias = (const float*)d_in[4];
  float* out = (float*)d_out;

  char* ws = (char*)d_ws;
  uint16_t* Xbf = (uint16_t*)(ws + XBF_OFF);
  uint16_t* T1  = (uint16_t*)(ws + T1_OFF);
  uint16_t* T1t = (uint16_t*)(ws + T1T_OFF);
  uint16_t* G2T = (uint16_t*)(ws + G2T_OFF);

  // 1) X -> bf16
  cvt_bf16<<<16384, 256, 0, stream>>>(x, Xbf);
  // 2) T1[(ijk)][(lb)] bf16, 4096x1024 row-major
  tt_t1<<<dim3(4, 128), 256, 0, stream>>>(g0, g1, T1);
  // 3) T1t = T1^T (1024x4096, k-contig) + g2t side-job
  transpose_t1<<<dim3(16, 64), 256, 0, stream>>>(T1, T1t, g2, G2T);
  // 4) fused: V = Xbf @ T1 (in-reg, dbuf-pipelined) then out = V @ g2 + bias
  gemm_fused<<<dim3(64, 8), 256, 0, stream>>>(Xbf, T1t, G2T, bias, out);
}